// Round 2
// baseline (98.896 us; speedup 1.0000x reference)
//
#include <hip/hip_runtime.h>
#include <stdint.h>

// Problem constants (fixed by reference setup_inputs)
#define B_      8
#define N_      48
#define M_      (N_ * N_)       // 2304 vectors per batch
#define ROWS    18              // rows of the pair matrix per block
#define CPB     (M_ / ROWS)     // 128 chunks per batch (power of 2!)
#define NBLK    (B_ * CPB)      // 1024 blocks = exactly 4 per CU, no tail
#define TPB     256

// ws layout
#define WS_PARTS_OFF   0                          // float  partS[NBLK]
#define WS_PARTC_OFF   (NBLK * sizeof(float))     // uint   partC[NBLK]
#define WS_TICKET_OFF  (2 * NBLK * sizeof(float)) // uint   ticket

// Single fused kernel: each block = (batch, 18-row chunk). Builds the
// per-batch vector table (vx, vy, 1/norm) in LDS, sweeps all 18 rows in ONE
// pass over the 2304 columns (each ds_read_b128 reused 18x), block-reduces,
// then the last block to finish (threadfence+ticket) reduces the 1024
// partials in double and writes the final scalar.
__global__ __launch_bounds__(TPB, 4) void fused_kernel(
    const float* __restrict__ gt,    // [B, 48, 2]
    const float* __restrict__ sm,    // [B, 48, 48]
    const float* __restrict__ thrp,  // [1]
    float* __restrict__ partS,
    unsigned int* __restrict__ partC,
    unsigned int* __restrict__ ticket,
    float* __restrict__ out)
{
    __shared__ float4 tile[M_];      // (vx, vy, w=1/norm, pad) : 36 KB
    __shared__ float  gx[N_], gy[N_];
    __shared__ float  redS[4];
    __shared__ unsigned int redC[4];
    __shared__ int amLast;

    const int tid   = threadIdx.x;
    const int b     = blockIdx.x >> 7;        // / CPB
    const int chunk = blockIdx.x & (CPB - 1); // % CPB

    if (tid < N_) {
        float2 g = ((const float2*)gt)[b * N_ + tid];
        gx[tid] = g.x;
        gy[tid] = g.y;
    }
    __syncthreads();

    const float thr = thrp[0];
    // Build vector table: v = (gt[i]-gt[j]) * sm_thresholded, w = rsqrt(|v|^2 + 2e-9)
    for (int idx = tid; idx < M_; idx += TPB) {   // 9 iterations
        float s = sm[b * M_ + idx];
        s = (s < thr) ? 0.0f : s;
        int i = idx / N_;
        int j = idx - i * N_;
        // exact IEEE single ops; matches numpy's (gt_i - gt_j) * sm
        float vx = __fmul_rn(__fsub_rn(gx[i], gx[j]), s);
        float vy = __fmul_rn(__fsub_rn(gy[i], gy[j]), s);
        float ss = vx * vx + vy * vy + 2e-9f;
        tile[idx] = make_float4(vx, vy, rsqrtf(ss), 0.0f);
    }
    __syncthreads();

    const int m0 = chunk * ROWS;
    float rx[ROWS], ry[ROWS], rw[ROWS], acc[ROWS];
    #pragma unroll
    for (int r = 0; r < ROWS; ++r) {
        float4 t = tile[m0 + r];   // wave-uniform LDS broadcast (free)
        rx[r] = t.x; ry[r] = t.y; rw[r] = t.z; acc[r] = 0.0f;
    }

    unsigned int cnt = 0;
    for (int n = tid; n < M_; n += TPB) {      // 9 iterations
        const float4 c = tile[n];              // one ds_read_b128, reused x18 rows
        #pragma unroll
        for (int r = 0; r < ROWS; ++r) {
            // discrete mul/mul/add (no fma contraction) so the exact-zero
            // count matches the fp32 reference semantics (absmax was 0.0)
            float d = __fadd_rn(__fmul_rn(rx[r], c.x), __fmul_rn(ry[r], c.y));
            cnt += (d != 0.0f) ? 1u : 0u;
            acc[r] = fmaf(fabsf(d), c.z, acc[r]);
        }
    }

    float total = 0.0f;
    #pragma unroll
    for (int r = 0; r < ROWS; ++r)
        total = fmaf(acc[r], rw[r], total);    // hoisted row-norm divide

    // wave64 shuffle reduce, then cross-wave via LDS
    for (int off = 32; off > 0; off >>= 1) {
        total += __shfl_down(total, off, 64);
        cnt   += __shfl_down(cnt,   off, 64);
    }
    const int wave = tid >> 6;
    if ((tid & 63) == 0) { redS[wave] = total; redC[wave] = cnt; }
    __syncthreads();
    if (tid == 0) {
        partS[blockIdx.x] = redS[0] + redS[1] + redS[2] + redS[3];
        partC[blockIdx.x] = redC[0] + redC[1] + redC[2] + redC[3];
        // release: make partials visible device-wide, then take a ticket
        __threadfence();
        unsigned int t = atomicAdd(ticket, 1u);
        amLast = (t == NBLK - 1) ? 1 : 0;
    }
    __syncthreads();

    if (amLast) {
        __threadfence();   // acquire: invalidate caches before reading partials
        __shared__ double rs[4], rc[4];
        double s = 0.0, c = 0.0;
        for (int i = tid; i < NBLK; i += TPB) {   // 4 iterations
            s += (double)partS[i];
            c += (double)partC[i];
        }
        for (int off = 32; off > 0; off >>= 1) {
            s += __shfl_down(s, off, 64);
            c += __shfl_down(c, off, 64);
        }
        if ((tid & 63) == 0) { rs[wave] = s; rc[wave] = c; }
        __syncthreads();
        if (tid == 0)
            out[0] = (float)((rs[0] + rs[1] + rs[2] + rs[3]) /
                             (rc[0] + rc[1] + rc[2] + rc[3]));
    }
}

extern "C" void kernel_launch(void* const* d_in, const int* in_sizes, int n_in,
                              void* d_out, int out_size, void* d_ws, size_t ws_size,
                              hipStream_t stream) {
    const float* gt  = (const float*)d_in[0];   // [8,48,2]
    const float* sm  = (const float*)d_in[1];   // [8,48,48]
    const float* thr = (const float*)d_in[2];   // [1]

    float*        partS  = (float*)((char*)d_ws + WS_PARTS_OFF);
    unsigned int* partC  = (unsigned int*)((char*)d_ws + WS_PARTC_OFF);
    unsigned int* ticket = (unsigned int*)((char*)d_ws + WS_TICKET_OFF);

    // zero the ticket (ws is poisoned to 0xAA before every launch)
    hipMemsetAsync(ticket, 0, sizeof(unsigned int), stream);
    fused_kernel<<<NBLK, TPB, 0, stream>>>(gt, sm, thr, partS, partC, ticket,
                                           (float*)d_out);
}